// Round 4
// baseline (1281.953 us; speedup 1.0000x reference)
//
#include <hip/hip_runtime.h>
#include <hip/hip_bf16.h>

typedef __bf16 bf16x8 __attribute__((ext_vector_type(8)));
typedef __bf16 bf16x4 __attribute__((ext_vector_type(4)));
typedef float  f32x4  __attribute__((ext_vector_type(4)));

#define N_IN 1024
#define BM   64
#define NTHR 640   // waves 0-7 consumers (MFMA), waves 8-9 producers (staging)

#define FENCE() asm volatile("" ::: "memory")
#define BARRIER() do { FENCE(); __builtin_amdgcn_s_barrier(); FENCE(); } while (0)

// Convert B (fp32, 1024x1024) to bf16 in workspace.
__global__ void convB_kernel(const float* __restrict__ B, __bf16* __restrict__ Bb) {
    int i = blockIdx.x * blockDim.x + threadIdx.x;
    f32x4 v = ((const f32x4*)B)[i];
    bf16x4 o;
    o[0] = (__bf16)v[0]; o[1] = (__bf16)v[1]; o[2] = (__bf16)v[2]; o[3] = (__bf16)v[3];
    ((bf16x4*)Bb)[i] = o;
}

// Producer/consumer wave-specialized fused kernel with DISJOINT role branches:
// producers stage o = num*avg^alpha (HBM-only vmcnt queue); consumers run MFMA
// with B prefetch (L2-only vmcnt queue). acc never crosses a divergent region.
template<bool USEBF>
__global__ __launch_bounds__(NTHR, 2)
void fused_kernel(const float* __restrict__ x, const float* __restrict__ A,
                  const float* __restrict__ Bf, const __bf16* __restrict__ Bb,
                  const float* __restrict__ Cp, const float* __restrict__ alpha,
                  float* __restrict__ out) {
    __shared__ __align__(16) __bf16 o_panel[BM * N_IN];   // 128 KB, XOR-swizzled
    __shared__ float rowsum[8][BM];                       // 2 KB

    const int t    = threadIdx.x;
    const int wave = t >> 6;
    const int lane = t & 63;
    const long blk_row = (long)blockIdx.x * BM;

    if (wave >= 8) {
        // ===================== producer (waves 8-9) =====================
        const int pt   = t - 512;          // 0..127
        const int prow = pt >> 1;          // 0..63
        const int pko  = (pt & 1) * 16;    // 0 or 16
        const float* xr = x + (blk_row + prow) * (2 * N_IN);
        const int sw    = (prow & 7) << 3;
        const int pbase = prow * N_IN;
        #pragma unroll 1
        for (int q = 0; q < 4; ++q) {
            #pragma unroll
            for (int c = 0; c < 8; ++c) {
                const int kb = (q * 8 + c) * 32 + pko;   // 16 consecutive k
                f32x4 va[4], vn[4], vl[4];
                #pragma unroll
                for (int u = 0; u < 4; ++u) {
                    va[u] = *(const f32x4*)(xr + kb + 4 * u);
                    vn[u] = *(const f32x4*)(xr + N_IN + kb + 4 * u);
                    vl[u] = *(const f32x4*)(alpha + kb + 4 * u);
                }
                bf16x8 w[2];
                #pragma unroll
                for (int u = 0; u < 4; ++u)
                    #pragma unroll
                    for (int e = 0; e < 4; ++e)
                        w[u >> 1][(u & 1) * 4 + e] =
                            (__bf16)(vn[u][e] * __expf(vl[u][e] * __logf(va[u][e])));
                *(bf16x8*)&o_panel[pbase + (kb ^ sw)]       = w[0];
                *(bf16x8*)&o_panel[pbase + ((kb + 8) ^ sw)] = w[1];
            }
            asm volatile("s_waitcnt lgkmcnt(0)" ::: "memory");
            __builtin_amdgcn_s_barrier();   // quarter q staged
            FENCE();
        }
        BARRIER();                          // match consumer epilogue barrier
    } else {
        // ===================== consumer (waves 0-7) =====================
        const int lrow = lane & 15;
        const int lgrp = lane >> 4;
        const int colbase = wave * 128;

        const __bf16* bp[8];
        const float*  fp[8];
        #pragma unroll
        for (int n = 0; n < 8; ++n) {
            const long i = colbase + n * 16 + lrow;
            if constexpr (USEBF) bp[n] = Bb + i * N_IN + lgrp * 8;
            else                 fp[n] = Bf + i * N_IN + lgrp * 8;
        }
        auto loadB = [&](bf16x8* dst, int kcv) {
            #pragma unroll
            for (int n = 0; n < 8; ++n) {
                if constexpr (USEBF) {
                    dst[n] = *(const bf16x8*)(bp[n] + kcv * 32);
                } else {
                    const float* p = fp[n] + kcv * 32;
                    f32x4 lo = *(const f32x4*)p;
                    f32x4 hi = *(const f32x4*)(p + 4);
                    #pragma unroll
                    for (int e = 0; e < 4; ++e) {
                        dst[n][e]     = (__bf16)lo[e];
                        dst[n][e + 4] = (__bf16)hi[e];
                    }
                }
            }
        };

        f32x4 acc[4][8];
        #pragma unroll
        for (int m = 0; m < 4; ++m)
            #pragma unroll
            for (int n = 0; n < 8; ++n)
                acc[m][n] = f32x4{0.f, 0.f, 0.f, 0.f};

        bf16x8 bufA[8], bufB[8];
        loadB(bufA, 0);                     // overlaps producer's q0 staging
        loadB(bufB, 1);

        #pragma unroll 1
        for (int q = 0; q < 4; ++q) {
            BARRIER();                      // quarter q staged by producer
            #pragma unroll
            for (int kq = 0; kq < 8; ++kq) {
                const int kc = q * 8 + kq;
                bf16x8* cur = (kq & 1) ? bufB : bufA;
                // A-frags from swizzled LDS
                bf16x8 afr[4];
                #pragma unroll
                for (int m = 0; m < 4; ++m) {
                    const int r  = m * 16 + lrow;
                    const int kk = (kc * 32 + lgrp * 8) ^ ((lrow & 7) << 3);
                    afr[m] = *(const bf16x8*)&o_panel[r * N_IN + kk];
                }
                #pragma unroll
                for (int m = 0; m < 4; ++m)
                    #pragma unroll
                    for (int n = 0; n < 8; ++n)
                        acc[m][n] = __builtin_amdgcn_mfma_f32_16x16x32_bf16(
                            afr[m], cur[n], acc[m][n], 0, 0, 0);
                if (kc + 2 < 32) loadB(cur, kc + 2);   // depth-2 B pipeline
            }
        }

        // ---- epilogue: rowpart[r] = sum_i (Y[r][i] + A[i]) * o[r][i] ----
        float rp[16];
        #pragma unroll
        for (int i = 0; i < 16; ++i) rp[i] = 0.f;
        #pragma unroll
        for (int n = 0; n < 8; ++n) {
            const int i = colbase + n * 16 + lrow;
            const float Ai = A[i];
            #pragma unroll
            for (int m = 0; m < 4; ++m)
                #pragma unroll
                for (int j = 0; j < 4; ++j) {
                    const int r = m * 16 + lgrp * 4 + j;   // C/D layout (m89-verified)
                    float ov = (float)o_panel[r * N_IN + ((i & ~7) ^ ((r & 7) << 3)) + (i & 7)];
                    rp[m * 4 + j] += (acc[m][n][j] + Ai) * ov;
                }
        }
        #pragma unroll
        for (int d = 1; d < 16; d <<= 1)
            #pragma unroll
            for (int i = 0; i < 16; ++i)
                rp[i] += __shfl_xor(rp[i], d);
        if (lrow == 0) {
            #pragma unroll
            for (int m = 0; m < 4; ++m)
                #pragma unroll
                for (int j = 0; j < 4; ++j)
                    rowsum[wave][m * 16 + lgrp * 4 + j] = rp[m * 4 + j];
        }
        asm volatile("s_waitcnt lgkmcnt(0)" ::: "memory");
        __builtin_amdgcn_s_barrier();       // rowsum visible
        FENCE();
        if (t < BM) {
            float s = Cp[0];
            #pragma unroll
            for (int w = 0; w < 8; ++w) s += rowsum[w][t];
            out[blk_row + t] = s;
        }
    }
}

extern "C" void kernel_launch(void* const* d_in, const int* in_sizes, int n_in,
                              void* d_out, int out_size, void* d_ws, size_t ws_size,
                              hipStream_t stream) {
    const float* x     = (const float*)d_in[0];
    const float* A     = (const float*)d_in[1];
    const float* B     = (const float*)d_in[2];
    const float* C     = (const float*)d_in[3];
    const float* alpha = (const float*)d_in[4];
    float* out = (float*)d_out;

    int batch = in_sizes[0] / (2 * N_IN);   // 65536
    int grid  = batch / BM;                 // 1024

    bool useBf = (ws_size >= (size_t)(N_IN * N_IN * sizeof(__bf16)));
    if (useBf) {
        __bf16* Bb = (__bf16*)d_ws;
        int nvec = (N_IN * N_IN) / 4;
        convB_kernel<<<nvec / 256, 256, 0, stream>>>(B, Bb);
        fused_kernel<true><<<grid, NTHR, 0, stream>>>(x, A, nullptr, Bb, C, alpha, out);
    } else {
        fused_kernel<false><<<grid, NTHR, 0, stream>>>(x, A, B, nullptr, C, alpha, out);
    }
}

// Round 5
// 446.604 us; speedup vs baseline: 2.8704x; 2.8704x over previous
//
#include <hip/hip_runtime.h>
#include <hip/hip_bf16.h>

typedef __bf16 bf16x8 __attribute__((ext_vector_type(8)));
typedef __bf16 bf16x4 __attribute__((ext_vector_type(4)));
typedef float  f32x4  __attribute__((ext_vector_type(4)));

#define N_IN 1024
#define BM   64
#define NTHR 512

// Convert B (fp32, 1024x1024) to bf16 in workspace.
__global__ void convB_kernel(const float* __restrict__ B, __bf16* __restrict__ Bb) {
    int i = blockIdx.x * blockDim.x + threadIdx.x;
    f32x4 v = ((const f32x4*)B)[i];
    bf16x4 o;
    o[0] = (__bf16)v[0]; o[1] = (__bf16)v[1]; o[2] = (__bf16)v[2]; o[3] = (__bf16)v[3];
    ((bf16x4*)Bb)[i] = o;
}

// Fused: o = num * avg^alpha (staged to LDS, 8-chunk-deep pipeline, 4 barriers),
// Y = O @ B^T via MFMA with both column-halves' acc live, then
// out[b] = sum_i o_i*(A_i + Y_i) + C.
// KEY ORDER: per iteration, B-loads (L2) are issued BEFORE x-staging loads (HBM)
// so the pre-MFMA s_waitcnt leaves the HBM loads in flight (in-order vmcnt).
template<bool USEBF>
__global__ __launch_bounds__(NTHR, 2)
void fused_kernel(const float* __restrict__ x, const float* __restrict__ A,
                  const float* __restrict__ Bf, const __bf16* __restrict__ Bb,
                  const float* __restrict__ Cp, const float* __restrict__ alpha,
                  float* __restrict__ out) {
    __shared__ __align__(16) __bf16 o_panel[BM * N_IN];   // 128 KB, XOR-swizzled
    __shared__ float rowsum[8][BM];                       // 2 KB

    const int t    = threadIdx.x;
    const int wave = t >> 6;
    const int lane = t & 63;
    const int lrow = lane & 15;   // frag row / col within 16
    const int lgrp = lane >> 4;   // k-group (0..3)
    const long blk_row = (long)blockIdx.x * BM;

    // staging role: 8 threads per row, 4 consecutive k each, 32-k chunks
    const int srow  = t >> 3;        // 0..63
    const int skoff = (t & 7) * 4;   // 0,4,...,28
    const float* xrow = x + (blk_row + srow) * (2 * N_IN);

    // ---- prologue: stage chunks 0..7 (k 0..255) ----
    #pragma unroll
    for (int c = 0; c < 8; ++c) {
        int k = c * 32 + skoff;
        f32x4 sa  = *(const f32x4*)(xrow + k);
        f32x4 sn  = *(const f32x4*)(xrow + N_IN + k);
        f32x4 sal = *(const f32x4*)(alpha + k);
        bf16x4 w4;
        #pragma unroll
        for (int e = 0; e < 4; ++e)
            w4[e] = (__bf16)(sn[e] * __expf(sal[e] * __logf(sa[e])));
        *(bf16x4*)&o_panel[srow * N_IN + ((k & ~7) ^ ((srow & 7) << 3)) + (k & 7)] = w4;
    }
    __syncthreads();

    f32x4 acc[2][4][4];
    #pragma unroll
    for (int h = 0; h < 2; ++h)
        #pragma unroll
        for (int m = 0; m < 4; ++m)
            #pragma unroll
            for (int n = 0; n < 4; ++n)
                acc[h][m][n] = f32x4{0.f, 0.f, 0.f, 0.f};

    // ---- main loop: 4 quarters x 8 kc; stage chunk kc+8 during iter kc ----
    #pragma unroll 1
    for (int q = 0; q < 4; ++q) {
        #pragma unroll
        for (int kq = 0; kq < 8; ++kq) {
            const int kc = q * 8 + kq;
            const bool staging = (q < 3);
            const int kk = kc * 32 + lgrp * 8;

            // (1) B-frag loads FIRST — oldest in the vmcnt queue (L2-hot, ~250cy)
            bf16x8 bfr[2][4];
            #pragma unroll
            for (int h = 0; h < 2; ++h)
                #pragma unroll
                for (int n = 0; n < 4; ++n) {
                    int i = h * 512 + wave * 64 + n * 16 + lrow;
                    if constexpr (USEBF) {
                        bfr[h][n] = *(const bf16x8*)&Bb[(long)i * N_IN + kk];
                    } else {
                        const float* p = Bf + (long)i * N_IN + kk;
                        f32x4 lo = *(const f32x4*)p;
                        f32x4 hi = *(const f32x4*)(p + 4);
                        #pragma unroll
                        for (int e = 0; e < 4; ++e) {
                            bfr[h][n][e]     = (__bf16)lo[e];
                            bfr[h][n][e + 4] = (__bf16)hi[e];
                        }
                    }
                }

            // (2) x-staging loads SECOND — younger; stay in flight across MFMA
            f32x4 sa, sn, sal;
            if (staging) {
                int k = (kc + 8) * 32 + skoff;
                sa  = *(const f32x4*)(xrow + k);
                sn  = *(const f32x4*)(xrow + N_IN + k);
                sal = *(const f32x4*)(alpha + k);
            }

            // (3) A-frags from swizzled LDS (lgkmcnt, independent counter)
            bf16x8 afr[4];
            #pragma unroll
            for (int m = 0; m < 4; ++m) {
                int r = m * 16 + lrow;
                afr[m] = *(const bf16x8*)&o_panel[r * N_IN + (kk ^ ((r & 7) << 3))];
            }

            // (4) MFMA cluster — waits B only (x loads outstanding)
            #pragma unroll
            for (int h = 0; h < 2; ++h)
                #pragma unroll
                for (int m = 0; m < 4; ++m)
                    #pragma unroll
                    for (int n = 0; n < 4; ++n)
                        acc[h][m][n] = __builtin_amdgcn_mfma_f32_16x16x32_bf16(
                            afr[m], bfr[h][n], acc[h][m][n], 0, 0, 0);

            // (5) pow + swizzled LDS write — drains this iter's x loads only
            if (staging) {
                int k = (kc + 8) * 32 + skoff;
                bf16x4 w4;
                #pragma unroll
                for (int e = 0; e < 4; ++e)
                    w4[e] = (__bf16)(sn[e] * __expf(sal[e] * __logf(sa[e])));
                *(bf16x4*)&o_panel[srow * N_IN + ((k & ~7) ^ ((srow & 7) << 3)) + (k & 7)] = w4;
            }
        }
        __syncthreads();   // quarter boundary: staged chunks visible
    }

    // ---- epilogue: rowpart[r] += (Y[r][i] + A[i]) * o[r][i] ----
    float rowpart[16];
    #pragma unroll
    for (int i = 0; i < 16; ++i) rowpart[i] = 0.f;
    #pragma unroll
    for (int h = 0; h < 2; ++h)
        #pragma unroll
        for (int n = 0; n < 4; ++n) {
            int i = h * 512 + wave * 64 + n * 16 + lrow;
            float Ai = A[i];
            #pragma unroll
            for (int m = 0; m < 4; ++m)
                #pragma unroll
                for (int j = 0; j < 4; ++j) {
                    int r = m * 16 + lgrp * 4 + j;    // C/D layout (m89-verified)
                    float y  = acc[h][m][n][j] + Ai;
                    float ov = (float)o_panel[r * N_IN + ((i & ~7) ^ ((r & 7) << 3)) + (i & 7)];
                    rowpart[m * 4 + j] += y * ov;
                }
        }

    // reduce over the 16 lanes sharing the same rows
    #pragma unroll
    for (int d = 1; d < 16; d <<= 1) {
        #pragma unroll
        for (int i = 0; i < 16; ++i)
            rowpart[i] += __shfl_xor(rowpart[i], d);
    }
    if (lrow == 0) {
        #pragma unroll
        for (int m = 0; m < 4; ++m)
            #pragma unroll
            for (int j = 0; j < 4; ++j)
                rowsum[wave][m * 16 + lgrp * 4 + j] = rowpart[m * 4 + j];
    }
    __syncthreads();
    if (t < BM) {
        float s = Cp[0];
        #pragma unroll
        for (int w = 0; w < 8; ++w) s += rowsum[w][t];
        out[blk_row + t] = s;
    }
}

extern "C" void kernel_launch(void* const* d_in, const int* in_sizes, int n_in,
                              void* d_out, int out_size, void* d_ws, size_t ws_size,
                              hipStream_t stream) {
    const float* x     = (const float*)d_in[0];
    const float* A     = (const float*)d_in[1];
    const float* B     = (const float*)d_in[2];
    const float* C     = (const float*)d_in[3];
    const float* alpha = (const float*)d_in[4];
    float* out = (float*)d_out;

    int batch = in_sizes[0] / (2 * N_IN);   // 65536
    int grid  = batch / BM;                 // 1024

    bool useBf = (ws_size >= (size_t)(N_IN * N_IN * sizeof(__bf16)));
    if (useBf) {
        __bf16* Bb = (__bf16*)d_ws;
        int nvec = (N_IN * N_IN) / 4;
        convB_kernel<<<nvec / 256, 256, 0, stream>>>(B, Bb);
        fused_kernel<true><<<grid, NTHR, 0, stream>>>(x, A, nullptr, Bb, C, alpha, out);
    } else {
        fused_kernel<false><<<grid, NTHR, 0, stream>>>(x, A, B, nullptr, C, alpha, out);
    }
}